// Round 7
// baseline (149.738 us; speedup 1.0000x reference)
//
#include <hip/hip_runtime.h>

typedef __attribute__((ext_vector_type(8))) _Float16 f16x8;
typedef __attribute__((ext_vector_type(4))) _Float16 f16x4;
typedef __attribute__((ext_vector_type(4))) float f32x4;

typedef __attribute__((address_space(3))) unsigned int lds_u32;
typedef const __attribute__((address_space(1))) unsigned int g_u32;

#define DEV_INLINE __device__ __forceinline__

constexpr int B_ = 128, N_ = 32, D_ = 256, H_ = 1024;
constexpr int XPAD = 260;   // fp32 X row stride in LDS
constexpr int SROW = 1032;  // f16 row stride of s16 tile (2064 B, 16B-multiple)

// Main-kernel LDS map (bytes):
//  [0,     16384)  wbuf0   (prologue overlay: X staging [32][260] f32 = 33280 B spans wbuf0/wbuf1/s16-head)
//  [16384, 32768)  wbuf1
//  [32768, 65792)  s16 [16][1032] f16  (rows 0-7 = j-local layer-1 sums, rows 8-15 zeroed)
//  [65792, 69888)  b1s [1024] f32
constexpr int LDS_MAIN = 69888;

DEV_INLINE void gload_lds16(const void* g, void* l) {
    __builtin_amdgcn_global_load_lds((g_u32*)g, (lds_u32*)l, 16, 0, 0);
}

#define BARRIER() asm volatile("s_barrier" ::: "memory")

// ---------------------------------------------------------------------------
// prep2: coalesced 32x32 LDS-tile transposes + f32->f16 cast.
//  W1T[h][k] = f16(W1[k][h])   (W1 [256][1024] -> W1T [1024][256])
//  W2T[d][h] = f16(W2[h][d])   (W2 [1024][256] -> W2T [256][1024])
// ---------------------------------------------------------------------------
__global__ void prep2(const float* __restrict__ W1, const float* __restrict__ W2,
                      _Float16* __restrict__ W1T, _Float16* __restrict__ W2T) {
    __shared__ float tile[32][36];
    const int t = threadIdx.x;
    const int r = t >> 3, cq = (t & 7) * 4;
    int bb = blockIdx.x;
    if (bb < 256) {
        int tk = bb >> 5, th = bb & 31; // k-tile, h-tile
        *(f32x4*)&tile[r][cq] = *(const f32x4*)(W1 + (size_t)(tk * 32 + r) * 1024 + th * 32 + cq);
        __syncthreads();
        f16x4 o;
        #pragma unroll
        for (int q = 0; q < 4; ++q) o[q] = (_Float16)tile[cq + q][r];
        *(f16x4*)(W1T + (size_t)(th * 32 + r) * 256 + tk * 32 + cq) = o;
    } else {
        bb -= 256;
        int th = bb >> 3, td = bb & 7;  // h-tile, d-tile
        *(f32x4*)&tile[r][cq] = *(const f32x4*)(W2 + (size_t)(th * 32 + r) * 256 + td * 32 + cq);
        __syncthreads();
        f16x4 o;
        #pragma unroll
        for (int q = 0; q < 4; ++q) o[q] = (_Float16)tile[cq + q][r];
        *(f16x4*)(W2T + (size_t)(td * 32 + r) * 1024 + th * 32 + cq) = o;
    }
}

// ---------------------------------------------------------------------------
// main (fused): grid = B * (N/8) = 512 blocks, 256 threads (4 waves),
// 2 blocks/CU (LDS 70KB, ~180 regs/wave -> 2 waves/SIMD from DIFFERENT blocks:
// desynced barriers let one block's MFMA overlap the other's stage/epilogue).
// Block owns 8 consecutive j's. Wave w handles j = j0+w and j0+4+w, so each
// W1 B-fragment LDS read feeds 4 MFMAs (2 rt x 2 j).
// W1T streamed in 32 chunks of 32 h-rows (16 KB), double-buffered, XOR-swizzled.
// Layer-1 row-sums -> s16 LDS tile; fused layer-2 tail (M=16, rows 8-15 zero):
// out[j][d] = s16[j][:] @ W2T[d][:] + 32*b2[d].
// ---------------------------------------------------------------------------
__global__ __launch_bounds__(256, 2)
void interaction_main(const float* __restrict__ Xg, const float* __restrict__ b1g,
                      const float* __restrict__ b2g, const _Float16* __restrict__ W1T,
                      const _Float16* __restrict__ W2T, float* __restrict__ outg) {
    __shared__ __align__(16) unsigned char smem[LDS_MAIN];

    const int tid = threadIdx.x;
    const int w = tid >> 6, l = tid & 63, l15 = l & 15, lg = l >> 4;
    const int bid = blockIdx.x;
    const int b = bid >> 2, jg = bid & 3;
    const int j0 = jg * 8;

    float*     Xs  = (float*)smem;
    _Float16*  s16 = (_Float16*)(smem + 32768);
    float*     b1s = (float*)(smem + 65792);

    // ---- prologue: X_b -> LDS (padded), b1 -> LDS ----
    {
        const float* xb = Xg + (size_t)b * (N_ * D_);
        int row = tid >> 3, c0 = (tid & 7) * 32;
        #pragma unroll
        for (int q = 0; q < 8; ++q)
            *(f32x4*)(Xs + row * XPAD + c0 + q * 4) = *(const f32x4*)(xb + row * 256 + c0 + q * 4);
        #pragma unroll
        for (int q = 0; q < 4; ++q) b1s[tid + q * 256] = b1g[tid + q * 256];
    }
    __syncthreads();

    // ---- build A fragments for both j's: P[i][k] = X[i][k] * X[j][k], fp16 ----
    // wave rows: i = rt*16 + l15 (rt=0,1); per-lane k = ks*32 + lg*8 + [0..7]
    f16x8 afrag[2][2][8]; // [jj][rt][ks]
    {
        const float* xja = Xs + (j0 + w) * XPAD;
        const float* xjb = Xs + (j0 + 4 + w) * XPAD;
        #pragma unroll
        for (int ks = 0; ks < 8; ++ks) {
            int k0 = ks * 32 + lg * 8;
            f32x4 jA0 = *(const f32x4*)(xja + k0);
            f32x4 jA1 = *(const f32x4*)(xja + k0 + 4);
            f32x4 jB0 = *(const f32x4*)(xjb + k0);
            f32x4 jB1 = *(const f32x4*)(xjb + k0 + 4);
            #pragma unroll
            for (int rt = 0; rt < 2; ++rt) {
                const float* xi = Xs + (rt * 16 + l15) * XPAD + k0;
                f32x4 x0 = *(const f32x4*)(xi);
                f32x4 x1 = *(const f32x4*)(xi + 4);
                f16x8 a, c;
                a[0] = (_Float16)(x0[0] * jA0[0]); c[0] = (_Float16)(x0[0] * jB0[0]);
                a[1] = (_Float16)(x0[1] * jA0[1]); c[1] = (_Float16)(x0[1] * jB0[1]);
                a[2] = (_Float16)(x0[2] * jA0[2]); c[2] = (_Float16)(x0[2] * jB0[2]);
                a[3] = (_Float16)(x0[3] * jA0[3]); c[3] = (_Float16)(x0[3] * jB0[3]);
                a[4] = (_Float16)(x1[0] * jA1[0]); c[4] = (_Float16)(x1[0] * jB1[0]);
                a[5] = (_Float16)(x1[1] * jA1[1]); c[5] = (_Float16)(x1[1] * jB1[1]);
                a[6] = (_Float16)(x1[2] * jA1[2]); c[6] = (_Float16)(x1[2] * jB1[2]);
                a[7] = (_Float16)(x1[3] * jA1[3]); c[7] = (_Float16)(x1[3] * jB1[3]);
                afrag[0][rt][ks] = a;
                afrag[1][rt][ks] = c;
            }
        }
    }
    __syncthreads(); // X region free -> becomes wbuf0/wbuf1/s16

    // zero s16 rows 8-15 (cols incl. pad) — after X overlay is dead
    for (int i = tid; i < 8 * SROW; i += 256) s16[8 * SROW + i] = (_Float16)0.f;

    // ---- stage W1 chunk c (32 rows x 512 B = 16 KB) into buf (c&1):
    //      linear LDS dest, inverse-XOR-swizzled global source ----
    auto stage = [&](int c) {
        const int bufbase = (c & 1) * 16384;
        #pragma unroll
        for (int p = 0; p < 4; ++p) {
            int hc   = (w << 3) + (p << 1) + (l >> 5);    // row 0..31 within chunk
            int srco = ((l & 31) ^ (hc & 7)) << 3;        // permuted k-oct
            const _Float16* src = W1T + (size_t)(c * 32 + hc) * 256 + srco;
            void* dst = smem + bufbase + w * 4096 + p * 1024; // wave-uniform
            gload_lds16(src, dst);
        }
    };

    stage(0);

    for (int c = 0; c < 32; ++c) {
        if (c < 31) {
            stage(c + 1);
            asm volatile("s_waitcnt vmcnt(4)" ::: "memory"); // stage(c) landed
        } else {
            asm volatile("s_waitcnt vmcnt(0)" ::: "memory");
        }
        BARRIER();

        const int bufbase = (c & 1) * 16384;
        f32x4 acc[2][2][2] = {}; // [jj][rt][ct]
        __builtin_amdgcn_s_setprio(1);
        #pragma unroll
        for (int ks = 0; ks < 8; ++ks) {
            #pragma unroll
            for (int ct = 0; ct < 2; ++ct) {
                int hc = ct * 16 + l15;
                int boff = bufbase + hc * 512 + ((ks * 64 + lg * 16) ^ ((hc & 7) << 4));
                f16x8 bfr = *(const f16x8*)(smem + boff);
                acc[0][0][ct] = __builtin_amdgcn_mfma_f32_16x16x32_f16(afrag[0][0][ks], bfr, acc[0][0][ct], 0, 0, 0);
                acc[0][1][ct] = __builtin_amdgcn_mfma_f32_16x16x32_f16(afrag[0][1][ks], bfr, acc[0][1][ct], 0, 0, 0);
                acc[1][0][ct] = __builtin_amdgcn_mfma_f32_16x16x32_f16(afrag[1][0][ks], bfr, acc[1][0][ct], 0, 0, 0);
                acc[1][1][ct] = __builtin_amdgcn_mfma_f32_16x16x32_f16(afrag[1][1][ks], bfr, acc[1][1][ct], 0, 0, 0);
            }
        }
        __builtin_amdgcn_s_setprio(0);

        // epilogue: +b1, ReLU, reduce over 32 i-rows per j, store f16 to s16
        #pragma unroll
        for (int ct = 0; ct < 2; ++ct) {
            int hcol = c * 32 + ct * 16 + l15;
            float bv = b1s[hcol];
            float v0 = 0.f, v1 = 0.f;
            #pragma unroll
            for (int rt = 0; rt < 2; ++rt)
                #pragma unroll
                for (int r = 0; r < 4; ++r) {
                    v0 += fmaxf(acc[0][rt][ct][r] + bv, 0.f);
                    v1 += fmaxf(acc[1][rt][ct][r] + bv, 0.f);
                }
            v0 += __shfl_xor(v0, 16, 64);
            v0 += __shfl_xor(v0, 32, 64);
            v1 += __shfl_xor(v1, 16, 64);
            v1 += __shfl_xor(v1, 32, 64);
            if (lg < 2) { // lanes 0-15 store j-local w; lanes 16-31 store w+4
                int row = w + (lg << 2);
                s16[row * SROW + hcol] = (_Float16)(lg ? v1 : v0);
            }
        }
        BARRIER(); // buf(c&1) fully read before restage at c+2
    }

    __syncthreads(); // s16 complete & visible to all waves

    // ---- fused layer 2: out[j][d] = s16[j][:] @ W2T[d][:] + 32*b2[d] ----
    // A rows = j-local 0..7 (8..15 zero); wave w owns d in [w*64, w*64+64).
    f32x4 acc2[4] = {};
    #pragma unroll
    for (int ks = 0; ks < 32; ++ks) {
        f16x8 af = *(const f16x8*)(s16 + l15 * SROW + ks * 32 + lg * 8);
        #pragma unroll
        for (int t2 = 0; t2 < 4; ++t2) {
            const _Float16* bp = W2T + (size_t)((w * 4 + t2) * 16 + l15) * 1024 + ks * 32 + lg * 8;
            f16x8 bf = *(const f16x8*)bp;
            acc2[t2] = __builtin_amdgcn_mfma_f32_16x16x32_f16(af, bf, acc2[t2], 0, 0, 0);
        }
    }
    if (lg < 2) { // valid output rows jloc = lg*4+r in 0..7
        #pragma unroll
        for (int t2 = 0; t2 < 4; ++t2) {
            int d = (w * 4 + t2) * 16 + l15;
            float bb = 32.f * b2g[d];
            #pragma unroll
            for (int r = 0; r < 4; ++r) {
                int jloc = lg * 4 + r;
                outg[(size_t)(b * 32 + j0 + jloc) * 256 + d] = acc2[t2][r] + bb;
            }
        }
    }
}

// ---------------------------------------------------------------------------
extern "C" void kernel_launch(void* const* d_in, const int* in_sizes, int n_in,
                              void* d_out, int out_size, void* d_ws, size_t ws_size,
                              hipStream_t stream) {
    const float* X  = (const float*)d_in[0]; // [128,32,256]
    const float* W1 = (const float*)d_in[1]; // [256,1024]
    const float* b1 = (const float*)d_in[2]; // [1024]
    const float* W2 = (const float*)d_in[3]; // [1024,256]
    const float* b2 = (const float*)d_in[4]; // [256]
    float* out = (float*)d_out;              // [128,32,256]

    _Float16* W1T = (_Float16*)d_ws;         // [1024][256]  512 KB
    _Float16* W2T = W1T + 262144;            // [256][1024]  512 KB

    prep2<<<dim3(512), dim3(256), 0, stream>>>(W1, W2, W1T, W2T);
    interaction_main<<<dim3(B_ * (N_ / 8)), dim3(256), 0, stream>>>(X, b1, b2, W1T, W2T, out);
}